// Round 12
// baseline (307.783 us; speedup 1.0000x reference)
//
#include <hip/hip_runtime.h>
#include <math.h>

// MemoryGraphBackprop forward: 64-step recurrence over sparse neuron graph.
// BS=2, T=64, C=64, D=64, N=1024, K=32.
// received[b,n,:] = sum_k w[n,k] * pm_prev[b, idx[n,k], :]
// h = d_t*h + (1-d_t)*(received + l2norm(cc_t) on first C neurons)
// pm = tanh(h*prim);  out[b,t] = pm[:, :C]
//
// R12 = R11 (D-decomposition: 128 independent (b,d) recurrences, pm[1024] f32
// double-buffered in LDS, one __syncthreads per step, no inter-WG traffic)
// + the two fixes R11's counters demanded:
//  1) BANK-SCHEDULED GATHER: per-neuron (idx,w) reordered in a prologue --
//     sorted by LDS bank (idx&31), rotated by (n&31). At slot s, lane l hits
//     bank ~(s+l)&31 -> ~2 lanes/bank (2-way is free) instead of random
//     4-5-way. Conflicts were ~50% of step time (1.74e7 cycles).
//  2) FORCED REGISTER RESIDENCY: idx/w held in named int4/float4 vars
//     (compile-time .xyzw only). R11's VGPR_Count=44 proved the compiler
//     demoted the arrays and re-read them from cache every step.
//     Byte-offset indices (idx*4) shave the per-access shift.

#define NN   1024
#define TT   64
#define CCn  64
#define DD   64
#define KC   32
#define TPB  1024

__device__ __forceinline__ float fast_tanh(float x) {
    x = fminf(9.0f, fmaxf(-9.0f, x));
    const float e = __expf(2.0f * x);
    return (e - 1.0f) / (e + 1.0f);
}

__device__ __forceinline__ float ldsf(const float* base, int byteoff) {
    return *(const float*)((const char*)base + byteoff);
}

// ---- prologue A: L2-normalize cc rows, transpose to ccn[d][b][t][c] ----
__global__ __launch_bounds__(256) void mg_prep(const float* __restrict__ cc,
                                               float* __restrict__ ccn) {
    const int lane = threadIdx.x & 63;             // = d
    const int wv   = threadIdx.x >> 6;
    const int row  = (int)blockIdx.x * 4 + wv;     // 0..8191 = ((b*64)+t)*64+c
    const float v = cc[row * DD + lane];
    float ss = v * v;
    #pragma unroll
    for (int off = 32; off >= 1; off >>= 1) ss += __shfl_xor(ss, off, 64);
    const float nv = v / fmaxf(sqrtf(ss), 1e-8f);
    const int c = row & 63;
    const int t = (row >> 6) & 63;
    const int b = row >> 12;
    ccn[(((lane * 2 + b) * TT) + t) * CCn + c] = nv;
}

// ---- prologue B: bank-sort + rotate each neuron's (idx,w) list ----------
__global__ __launch_bounds__(256) void mg_sort(const int* __restrict__ cidx,
                                               const float* __restrict__ cw,
                                               int* __restrict__ idx2,
                                               float* __restrict__ w2) {
    const int n = (int)blockIdx.x * 256 + (int)threadIdx.x;   // 0..1023
    int   ib[KC];
    float wb[KC];
    #pragma unroll
    for (int k = 0; k < KC; ++k) { ib[k] = cidx[n * KC + k]; wb[k] = cw[n * KC + k]; }
    // insertion sort by bank = idx & 31
    for (int i = 1; i < KC; ++i) {
        const int vi = ib[i]; const float vw = wb[i];
        const int key = vi & 31;
        int j = i - 1;
        while (j >= 0 && (ib[j] & 31) > key) { ib[j + 1] = ib[j]; wb[j + 1] = wb[j]; --j; }
        ib[j + 1] = vi; wb[j + 1] = vw;
    }
    const int rot = n & 31;                        // lane phase
    for (int s = 0; s < KC; ++s) {
        const int p = (s + rot) & 31;
        idx2[n * KC + s] = ib[p] * 4;              // byte offset
        w2[n * KC + s]   = wb[p];
    }
}

__global__ __launch_bounds__(TPB) void mg_main(
    const int*   __restrict__ eot,    // [BS,T]
    const int*   __restrict__ idx2,   // [N,K] byte offsets, bank-scheduled
    const float* __restrict__ w2,     // [N,K] matching weights
    const float* __restrict__ prim,   // [N,D]
    const float* __restrict__ dlog,   // [N]
    const float* __restrict__ h0,     // [BS,N,D]
    const float* __restrict__ pm0,    // [BS,N,D]
    const float* __restrict__ ccn,    // [D][BS][T][C] prenormalized cc
    float*       __restrict__ out)    // [BS,T,C,D]
{
    __shared__ float pmf[2][NN];

    const int tid = (int)threadIdx.x;              // = neuron n
    const int wg  = (int)blockIdx.x;               // 0..127
    const int d   = wg & 63;
    const int b   = wg >> 6;

    // graph constants in NAMED vector registers (compile-time access only)
    const int4*   ip = (const int4*)(idx2 + tid * KC);
    const float4* wp = (const float4*)(w2 + tid * KC);
    const int4   i0 = ip[0], i1 = ip[1], i2 = ip[2], i3 = ip[3],
                 i4 = ip[4], i5 = ip[5], i6 = ip[6], i7 = ip[7];
    const float4 w0 = wp[0], w1 = wp[1], w2v = wp[2], w3 = wp[3],
                 w4 = wp[4], w5 = wp[5], w6 = wp[6], w7 = wp[7];

    const float pv  = prim[tid * DD + d];
    const float dec = 1.0f / (1.0f + __expf(-dlog[tid]));
    float h = h0[(b * NN + tid) * DD + d];
    pmf[0][tid] = pm0[(b * NN + tid) * DD + d];

    const int lane = tid & 63;
    const unsigned long long em = __ballot(eot[b * TT + lane] != 0);  // bit t

    const float* ccb = ccn + (size_t)(d * 2 + b) * TT * CCn;          // [t][c]

    __syncthreads();

    for (int t = 0; t < TT; ++t) {
        const float* src = pmf[t & 1];
        float*       dst = pmf[(t + 1) & 1];

        float a0 = 0.f, a1 = 0.f, a2 = 0.f, a3 = 0.f;
#define G4(iv, wv)                                  \
        a0 = fmaf(wv.x, ldsf(src, iv.x), a0);       \
        a1 = fmaf(wv.y, ldsf(src, iv.y), a1);       \
        a2 = fmaf(wv.z, ldsf(src, iv.z), a2);       \
        a3 = fmaf(wv.w, ldsf(src, iv.w), a3);
        G4(i0, w0) G4(i1, w1) G4(i2, w2v) G4(i3, w3)
        G4(i4, w4) G4(i5, w5) G4(i6, w6)  G4(i7, w7)
#undef G4
        float recv = (a0 + a1) + (a2 + a3);

        if (tid < CCn) recv += ccb[t * CCn + tid];   // wave-0 only, coalesced

        const float e  = (float)((em >> t) & 1ull);
        const float dt = dec * (1.0f - e);
        h = dt * h + (1.0f - dt) * recv;
        const float pmv = fast_tanh(h * pv);

        dst[tid] = pmv;
        if (tid < CCn)
            out[((size_t)(b * TT + t) * CCn + tid) * DD + d] = pmv;

        __syncthreads();                             // one barrier per step
    }
}

extern "C" void kernel_launch(void* const* d_in, const int* in_sizes, int n_in,
                              void* d_out, int out_size, void* d_ws, size_t ws_size,
                              hipStream_t stream) {
    const float* cc   = (const float*)d_in[0];   // cc_signals [2,64,64,64] f32
    const int*   eot  = (const int*)  d_in[1];   // eot_mask   [2,64]
    const int*   cidx = (const int*)  d_in[2];   // conn_indices [1024,32]
    /* d_in[3] conn_mask: all ones -> unused */
    const float* prim = (const float*)d_in[4];   // primitives [1024,64]
    const float* cw   = (const float*)d_in[5];   // conn_weights [1024,32]
    const float* dlog = (const float*)d_in[6];   // decay_logit [1024]
    const float* h0   = (const float*)d_in[7];   // h0 [2,1024,64]
    const float* pm0  = (const float*)d_in[8];   // prev_msg0 [2,1024,64]
    /* d_in[9] grad_window: forward no-op */

    float* ccn  = (float*)d_ws;                          // 2 MB
    int*   idx2 = (int*)(ccn + (size_t)DD * 2 * TT * CCn);
    float* w2   = (float*)(idx2 + NN * KC);

    hipLaunchKernelGGL(mg_prep, dim3(2 * TT * CCn / 4), dim3(256), 0, stream,
                       cc, ccn);
    hipLaunchKernelGGL(mg_sort, dim3(NN / 256), dim3(256), 0, stream,
                       cidx, cw, idx2, w2);
    hipLaunchKernelGGL(mg_main, dim3(2 * DD), dim3(TPB), 0, stream,
                       eot, idx2, w2, prim, dlog, h0, pm0, ccn, (float*)d_out);
}

// Round 13
// 192.958 us; speedup vs baseline: 1.5951x; 1.5951x over previous
//
#include <hip/hip_runtime.h>
#include <math.h>

// MemoryGraphBackprop forward: 64-step recurrence over sparse neuron graph.
// BS=2, T=64, C=64, D=64, N=1024, K=32.
// received[b,n,:] = sum_k w[n,k] * pm_prev[b, idx[n,k], :]
// h = d_t*h + (1-d_t)*(received + l2norm(cc_t) on first C neurons)
// pm = tanh(h*prim);  out[b,t] = pm[:, :C]
//
// R13 = R12 (D-decomposition, bank-scheduled register-resident gather) with
// the sort prologue rewritten. R12's mg_sort took 124us (!) -- runtime-indexed
// local arrays spilled to scratch (rule #20) at 0.17% occupancy. Replacement:
// wave-parallel bitonic sort -- each neuron's 32 (idx,w) entries live one-per-
// lane in a 32-lane half-wave; sort by bank key via 15 XOR-partner compare-
// exchange stages (all __shfl_xor, compile-time patterns, zero scratch);
// rotation by n&31 applied on write-out. 512 waves grid-wide, ~2-3us.
// mg_prep / mg_main identical to R12 (isolates the fix + reveals mg_main PMC).

#define NN   1024
#define TT   64
#define CCn  64
#define DD   64
#define KC   32
#define TPB  1024

__device__ __forceinline__ float fast_tanh(float x) {
    x = fminf(9.0f, fmaxf(-9.0f, x));
    const float e = __expf(2.0f * x);
    return (e - 1.0f) / (e + 1.0f);
}

__device__ __forceinline__ float ldsf(const float* base, int byteoff) {
    return *(const float*)((const char*)base + byteoff);
}

// ---- prologue A: L2-normalize cc rows, transpose to ccn[d][b][t][c] ----
__global__ __launch_bounds__(256) void mg_prep(const float* __restrict__ cc,
                                               float* __restrict__ ccn) {
    const int lane = threadIdx.x & 63;             // = d
    const int wv   = threadIdx.x >> 6;
    const int row  = (int)blockIdx.x * 4 + wv;     // 0..8191 = ((b*64)+t)*64+c
    const float v = cc[row * DD + lane];
    float ss = v * v;
    #pragma unroll
    for (int off = 32; off >= 1; off >>= 1) ss += __shfl_xor(ss, off, 64);
    const float nv = v / fmaxf(sqrtf(ss), 1e-8f);
    const int c = row & 63;
    const int t = (row >> 6) & 63;
    const int b = row >> 12;
    ccn[(((lane * 2 + b) * TT) + t) * CCn + c] = nv;
}

// ---- prologue B: wave-parallel bitonic bank-sort + rotate -------------
// One neuron per 32-lane group; element s lives in lane s. Sort ascending
// by key = ((idx&31)<<5)|s (unique), payload (idx, w) shuffled alongside.
__global__ __launch_bounds__(256) void mg_sortb(const int* __restrict__ cidx,
                                                const float* __restrict__ cw,
                                                int* __restrict__ idx2,
                                                float* __restrict__ w2) {
    const int tid  = (int)threadIdx.x;
    const int lane = tid & 63;
    const int wv   = tid >> 6;                     // 0..3
    const int g    = lane >> 5;                    // half-wave 0/1
    const int s    = lane & 31;                    // slot within neuron
    const int n    = (int)blockIdx.x * 8 + wv * 2 + g;   // 0..1023

    int   idx = cidx[n * KC + s];
    float w   = cw[n * KC + s];
    int   key = ((idx & 31) << 5) | s;             // bank-major, unique

    #pragma unroll
    for (int k = 2; k <= 32; k <<= 1) {
        #pragma unroll
        for (int j = k >> 1; j >= 1; j >>= 1) {
            const int   ok = __shfl_xor(key, j, 64);   // partner stays in group (j<32)
            const int   oi = __shfl_xor(idx, j, 64);
            const float ow = __shfl_xor(w,   j, 64);
            const bool up      = ((s & k) == 0);       // ascending segment
            const bool lower   = ((s & j) == 0);       // lower element of pair
            const bool keepmin = (lower == up);
            const bool mine_min = key < ok;
            if (keepmin ? !mine_min : mine_min) { key = ok; idx = oi; w = ow; }
        }
    }

    const int rot  = n & 31;                       // lane phase
    const int dsts = (s - rot) & 31;               // idx2[n][dsts] = sorted[s]
    idx2[n * KC + dsts] = idx * 4;                 // byte offset
    w2[n * KC + dsts]   = w;
}

__global__ __launch_bounds__(TPB) void mg_main(
    const int*   __restrict__ eot,    // [BS,T]
    const int*   __restrict__ idx2,   // [N,K] byte offsets, bank-scheduled
    const float* __restrict__ w2,     // [N,K] matching weights
    const float* __restrict__ prim,   // [N,D]
    const float* __restrict__ dlog,   // [N]
    const float* __restrict__ h0,     // [BS,N,D]
    const float* __restrict__ pm0,    // [BS,N,D]
    const float* __restrict__ ccn,    // [D][BS][T][C] prenormalized cc
    float*       __restrict__ out)    // [BS,T,C,D]
{
    __shared__ float pmf[2][NN];

    const int tid = (int)threadIdx.x;              // = neuron n
    const int wg  = (int)blockIdx.x;               // 0..127
    const int d   = wg & 63;
    const int b   = wg >> 6;

    // graph constants in NAMED vector registers (compile-time access only)
    const int4*   ip = (const int4*)(idx2 + tid * KC);
    const float4* wp = (const float4*)(w2 + tid * KC);
    const int4   i0 = ip[0], i1 = ip[1], i2 = ip[2], i3 = ip[3],
                 i4 = ip[4], i5 = ip[5], i6 = ip[6], i7 = ip[7];
    const float4 w0 = wp[0], w1 = wp[1], w2v = wp[2], w3 = wp[3],
                 w4 = wp[4], w5 = wp[5], w6 = wp[6], w7 = wp[7];

    const float pv  = prim[tid * DD + d];
    const float dec = 1.0f / (1.0f + __expf(-dlog[tid]));
    float h = h0[(b * NN + tid) * DD + d];
    pmf[0][tid] = pm0[(b * NN + tid) * DD + d];

    const int lane = tid & 63;
    const unsigned long long em = __ballot(eot[b * TT + lane] != 0);  // bit t

    const float* ccb = ccn + (size_t)(d * 2 + b) * TT * CCn;          // [t][c]

    __syncthreads();

    for (int t = 0; t < TT; ++t) {
        const float* src = pmf[t & 1];
        float*       dst = pmf[(t + 1) & 1];

        float a0 = 0.f, a1 = 0.f, a2 = 0.f, a3 = 0.f;
#define G4(iv, wv)                                  \
        a0 = fmaf(wv.x, ldsf(src, iv.x), a0);       \
        a1 = fmaf(wv.y, ldsf(src, iv.y), a1);       \
        a2 = fmaf(wv.z, ldsf(src, iv.z), a2);       \
        a3 = fmaf(wv.w, ldsf(src, iv.w), a3);
        G4(i0, w0) G4(i1, w1) G4(i2, w2v) G4(i3, w3)
        G4(i4, w4) G4(i5, w5) G4(i6, w6)  G4(i7, w7)
#undef G4
        float recv = (a0 + a1) + (a2 + a3);

        if (tid < CCn) recv += ccb[t * CCn + tid];   // wave-0 only, coalesced

        const float e  = (float)((em >> t) & 1ull);
        const float dt = dec * (1.0f - e);
        h = dt * h + (1.0f - dt) * recv;
        const float pmv = fast_tanh(h * pv);

        dst[tid] = pmv;
        if (tid < CCn)
            out[((size_t)(b * TT + t) * CCn + tid) * DD + d] = pmv;

        __syncthreads();                             // one barrier per step
    }
}

extern "C" void kernel_launch(void* const* d_in, const int* in_sizes, int n_in,
                              void* d_out, int out_size, void* d_ws, size_t ws_size,
                              hipStream_t stream) {
    const float* cc   = (const float*)d_in[0];   // cc_signals [2,64,64,64] f32
    const int*   eot  = (const int*)  d_in[1];   // eot_mask   [2,64]
    const int*   cidx = (const int*)  d_in[2];   // conn_indices [1024,32]
    /* d_in[3] conn_mask: all ones -> unused */
    const float* prim = (const float*)d_in[4];   // primitives [1024,64]
    const float* cw   = (const float*)d_in[5];   // conn_weights [1024,32]
    const float* dlog = (const float*)d_in[6];   // decay_logit [1024]
    const float* h0   = (const float*)d_in[7];   // h0 [2,1024,64]
    const float* pm0  = (const float*)d_in[8];   // prev_msg0 [2,1024,64]
    /* d_in[9] grad_window: forward no-op */

    float* ccn  = (float*)d_ws;                          // 2 MB
    int*   idx2 = (int*)(ccn + (size_t)DD * 2 * TT * CCn);
    float* w2   = (float*)(idx2 + NN * KC);

    hipLaunchKernelGGL(mg_prep, dim3(2 * TT * CCn / 4), dim3(256), 0, stream,
                       cc, ccn);
    hipLaunchKernelGGL(mg_sortb, dim3(NN / 8), dim3(256), 0, stream,
                       cidx, cw, idx2, w2);
    hipLaunchKernelGGL(mg_main, dim3(2 * DD), dim3(TPB), 0, stream,
                       eot, idx2, w2, prim, dlog, h0, pm0, ccn, (float*)d_out);
}

// Round 14
// 188.147 us; speedup vs baseline: 1.6359x; 1.0256x over previous
//
#include <hip/hip_runtime.h>
#include <math.h>

// MemoryGraphBackprop forward: 64-step recurrence over sparse neuron graph.
// BS=2, T=64, C=64, D=64, N=1024, K=32.
// received[b,n,:] = sum_k w[n,k] * pm_prev[b, idx[n,k], :]
// h = d_t*h + (1-d_t)*(received + l2norm(cc_t) on first C neurons)
// pm = tanh(h*prim);  out[b,t] = pm[:, :C]
//
// R14 = R11 structure (D-decomposition: 128 independent (b,d) recurrences,
// pm[1024] f32 double-buffered in LDS, one __syncthreads per step) with the
// three changes R13's counters demanded:
//  1) DROP bank scheduling (R13 proved conflicts unchanged 1.74->1.79e7).
//  2) DROP the 2MB ccn transpose: tiny norm-only prologue (32KB of 1/norms);
//     mg_main reads raw cc divergently in wave 0 only (L2-resident, hidden
//     under the other 15 waves' LDS gathers).
//  3) FORCE idx/w into registers: ext_vector types + inline-asm "+v"
//     keep-alive after load -- compiler cannot rematerialize past an asm def.
//     R11/R13's VGPR_Count=44 proved it was re-loading 256B/thread/step from
//     L2 (256 VMEM wave-instrs per WG-step on the issue path).

#define NN   1024
#define TT   64
#define CCn  64
#define DD   64
#define KC   32
#define TPB  1024

typedef int   i32x4 __attribute__((ext_vector_type(4)));
typedef float f32x4 __attribute__((ext_vector_type(4)));

__device__ __forceinline__ float fast_tanh(float x) {
    x = fminf(9.0f, fmaxf(-9.0f, x));
    const float e = __expf(2.0f * x);
    return (e - 1.0f) / (e + 1.0f);
}

__device__ __forceinline__ float ldsf(const float* base, int byteoff) {
    return *(const float*)((const char*)base + byteoff);
}

// ---- prologue: inverse L2 norms of cc rows -> invn[b][t][c] (32KB) ----
__global__ __launch_bounds__(256) void mg_norm(const float* __restrict__ cc,
                                               float* __restrict__ invn) {
    const int lane = threadIdx.x & 63;             // = d
    const int wv   = threadIdx.x >> 6;
    const int row  = (int)blockIdx.x * 4 + wv;     // 0..8191 = ((b*64)+t)*64+c
    const float v = cc[row * DD + lane];
    float ss = v * v;
    #pragma unroll
    for (int off = 32; off >= 1; off >>= 1) ss += __shfl_xor(ss, off, 64);
    if (lane == 0) invn[row] = 1.0f / fmaxf(sqrtf(ss), 1e-8f);
}

__global__ __launch_bounds__(TPB) void mg_main(
    const float* __restrict__ cc,     // [BS,T,C,D] raw
    const int*   __restrict__ eot,    // [BS,T]
    const int*   __restrict__ cidx,   // [N,K]
    const float* __restrict__ cw,     // [N,K]  (conn_mask all-ones; skipped)
    const float* __restrict__ prim,   // [N,D]
    const float* __restrict__ dlog,   // [N]
    const float* __restrict__ h0,     // [BS,N,D]
    const float* __restrict__ pm0,    // [BS,N,D]
    const float* __restrict__ invn,   // [BS,T,C] inverse norms
    float*       __restrict__ out)    // [BS,T,C,D]
{
    __shared__ float pmf[2][NN];

    const int tid = (int)threadIdx.x;              // = neuron n
    const int wg  = (int)blockIdx.x;               // 0..127
    const int d   = wg & 63;
    const int b   = wg >> 6;

    // graph constants: load once, pin in VGPRs via asm keep-alive
    const i32x4* ip = (const i32x4*)(cidx + tid * KC);
    const f32x4* wp = (const f32x4*)(cw + tid * KC);
    i32x4 i0 = ip[0] * 4, i1 = ip[1] * 4, i2 = ip[2] * 4, i3 = ip[3] * 4,
          i4 = ip[4] * 4, i5 = ip[5] * 4, i6 = ip[6] * 4, i7 = ip[7] * 4;
    f32x4 w0 = wp[0], w1 = wp[1], w2v = wp[2], w3 = wp[3],
          w4 = wp[4], w5 = wp[5], w6 = wp[6], w7 = wp[7];
    asm volatile("" : "+v"(i0), "+v"(i1), "+v"(i2), "+v"(i3),
                      "+v"(i4), "+v"(i5), "+v"(i6), "+v"(i7),
                      "+v"(w0), "+v"(w1), "+v"(w2v), "+v"(w3),
                      "+v"(w4), "+v"(w5), "+v"(w6), "+v"(w7));

    const float pv  = prim[tid * DD + d];
    const float dec = 1.0f / (1.0f + __expf(-dlog[tid]));
    float h = h0[(b * NN + tid) * DD + d];
    pmf[0][tid] = pm0[(b * NN + tid) * DD + d];

    const int lane = tid & 63;
    const unsigned long long em = __ballot(eot[b * TT + lane] != 0);  // bit t

    __syncthreads();

    for (int t = 0; t < TT; ++t) {
        const float* src = pmf[t & 1];
        float*       dst = pmf[(t + 1) & 1];

        // cc injection operands issued EARLY (wave 0 only; L2-resident;
        // divergent 64x4B but hidden under 15 other waves' LDS gathers)
        float ccraw = 0.0f, ccinv = 0.0f;
        if (tid < CCn) {
            const int rc = (b * TT + t) * CCn + tid;
            ccraw = cc[(size_t)rc * DD + d];
            ccinv = invn[rc];
        }

        float a0 = 0.f, a1 = 0.f, a2 = 0.f, a3 = 0.f;
#define G4(iv, wv)                                  \
        a0 = fmaf(wv.x, ldsf(src, iv.x), a0);       \
        a1 = fmaf(wv.y, ldsf(src, iv.y), a1);       \
        a2 = fmaf(wv.z, ldsf(src, iv.z), a2);       \
        a3 = fmaf(wv.w, ldsf(src, iv.w), a3);
        G4(i0, w0) G4(i1, w1) G4(i2, w2v) G4(i3, w3)
        G4(i4, w4) G4(i5, w5) G4(i6, w6)  G4(i7, w7)
#undef G4
        float recv = (a0 + a1) + (a2 + a3);
        recv += ccraw * ccinv;                       // 0 for tid >= CCn

        const float e  = (float)((em >> t) & 1ull);
        const float dt = dec * (1.0f - e);
        h = dt * h + (1.0f - dt) * recv;
        const float pmv = fast_tanh(h * pv);

        dst[tid] = pmv;
        if (tid < CCn)
            out[((size_t)(b * TT + t) * CCn + tid) * DD + d] = pmv;

        __syncthreads();                             // one barrier per step
    }
}

extern "C" void kernel_launch(void* const* d_in, const int* in_sizes, int n_in,
                              void* d_out, int out_size, void* d_ws, size_t ws_size,
                              hipStream_t stream) {
    const float* cc   = (const float*)d_in[0];   // cc_signals [2,64,64,64] f32
    const int*   eot  = (const int*)  d_in[1];   // eot_mask   [2,64]
    const int*   cidx = (const int*)  d_in[2];   // conn_indices [1024,32]
    /* d_in[3] conn_mask: all ones -> unused */
    const float* prim = (const float*)d_in[4];   // primitives [1024,64]
    const float* cw   = (const float*)d_in[5];   // conn_weights [1024,32]
    const float* dlog = (const float*)d_in[6];   // decay_logit [1024]
    const float* h0   = (const float*)d_in[7];   // h0 [2,1024,64]
    const float* pm0  = (const float*)d_in[8];   // prev_msg0 [2,1024,64]
    /* d_in[9] grad_window: forward no-op */

    float* invn = (float*)d_ws;                  // [2][64][64] = 32KB

    hipLaunchKernelGGL(mg_norm, dim3(2 * TT * CCn / 4), dim3(256), 0, stream,
                       cc, invn);
    hipLaunchKernelGGL(mg_main, dim3(2 * DD), dim3(TPB), 0, stream,
                       cc, eot, cidx, cw, prim, dlog, h0, pm0, invn,
                       (float*)d_out);
}